// Round 4
// baseline (1799.986 us; speedup 1.0000x reference)
//
#include <hip/hip_runtime.h>
#include <math.h>
#include <stdint.h>

#define NTOK 16384
#define KD   4096
#define EDIM 64
#define MT   32                 // tokens per block
#define KC   32                 // k per chunk
#define NC   (KD / KC)          // 128 chunks
#define WP   34                 // W column pad (floats): bank = (2c+k)%32 -> worst 2-way (free)
#define WSZ  (128 * WP)         // 4352 floats per W buffer
#define XOFF (2 * WSZ)          // 8704
#define XSZ  (MT * KC)          // 1024 floats per x buffer
#define SMEMF (XOFF + 2 * XSZ)  // 10752 floats = 43008 B

__global__ __launch_bounds__(256, 2)
void router_fused(const float* __restrict__ x,
                  const float* __restrict__ noise,
                  const float* __restrict__ Wr,
                  const float* __restrict__ br,
                  const float* __restrict__ Wn,
                  const float* __restrict__ bn,
                  float* __restrict__ out) {
    __shared__ float smem[SMEMF];
    const int tid = threadIdx.x;
    const int t0 = blockIdx.x * MT;

    // compute roles: thread = 4 tokens (tb..tb+3) x 4 spread cols (cg + 32j)
    const int cg = tid & 31;
    const int tb = (tid >> 5) * 4;

    // x staging: thread loads x[t0+xr][k0+xq .. +3]
    const int xr = tid >> 3;
    const int xq = (tid & 7) * 4;
    // W staging: thread loads W[k0+kb .. +3][cb .. cb+3] and transposes into LDS
    const int kb = (tid >> 5) * 4;
    const int cb = (tid & 31) * 4;
    const float* wsrc_base = (cb < 64) ? (Wr + cb) : (Wn + (cb - 64));
    const float* xsrc = x + (size_t)(t0 + xr) * KD + xq;

    float acc[4][4];
#pragma unroll
    for (int i = 0; i < 4; ++i)
#pragma unroll
        for (int j = 0; j < 4; ++j) acc[i][j] = 0.f;

    // ---- prologue: stage chunk 0 into buffer 0 ----
    {
        float4 xv  = *(const float4*)(xsrc);
        float4 wq0 = *(const float4*)(wsrc_base + (size_t)(kb + 0) * EDIM);
        float4 wq1 = *(const float4*)(wsrc_base + (size_t)(kb + 1) * EDIM);
        float4 wq2 = *(const float4*)(wsrc_base + (size_t)(kb + 2) * EDIM);
        float4 wq3 = *(const float4*)(wsrc_base + (size_t)(kb + 3) * EDIM);
        *(float4*)&smem[XOFF + xr * KC + xq] = xv;
        const float* q0 = (const float*)&wq0; const float* q1 = (const float*)&wq1;
        const float* q2 = (const float*)&wq2; const float* q3 = (const float*)&wq3;
#pragma unroll
        for (int i = 0; i < 4; ++i) {
            float2 lo; lo.x = q0[i]; lo.y = q1[i];
            float2 hi; hi.x = q2[i]; hi.y = q3[i];
            float* wd = &smem[(cb + i) * WP + kb];
            *(float2*)wd = lo;
            *(float2*)(wd + 2) = hi;
        }
    }
    __syncthreads();

    // ---- K loop: prefetch c+1 (global->regs), compute c (LDS), stage c+1, barrier ----
    for (int c = 0; c < NC; ++c) {
        const int bcur = c & 1;
        const bool pre = (c + 1) < NC;
        float4 xv, wq0, wq1, wq2, wq3;
        if (pre) {
            const size_t k0n = (size_t)(c + 1) * KC;
            xv  = *(const float4*)(xsrc + k0n);
            wq0 = *(const float4*)(wsrc_base + (k0n + kb + 0) * EDIM);
            wq1 = *(const float4*)(wsrc_base + (k0n + kb + 1) * EDIM);
            wq2 = *(const float4*)(wsrc_base + (k0n + kb + 2) * EDIM);
            wq3 = *(const float4*)(wsrc_base + (k0n + kb + 3) * EDIM);
        }

        const float* xb = &smem[XOFF + bcur * XSZ + tb * KC];
        const float* wb = &smem[bcur * WSZ];
#pragma unroll
        for (int kk = 0; kk < KC; kk += 4) {
            float xvv[4][4];
#pragma unroll
            for (int i = 0; i < 4; ++i)
                *(float4*)xvv[i] = *(const float4*)&xb[i * KC + kk];   // broadcast reads
            float wvv[4][4];
#pragma unroll
            for (int j = 0; j < 4; ++j) {
                const float* wp = &wb[(cg + 32 * j) * WP + kk];
                *(float2*)&wvv[j][0] = *(const float2*)wp;              // ds_read_b64, 2-way max
                *(float2*)&wvv[j][2] = *(const float2*)(wp + 2);
            }
            // strictly ascending k per accumulator (bit-identical to R1's chain)
#pragma unroll
            for (int i = 0; i < 4; ++i)
#pragma unroll
                for (int j = 0; j < 4; ++j) {
                    acc[i][j] = fmaf(xvv[i][0], wvv[j][0], acc[i][j]);
                    acc[i][j] = fmaf(xvv[i][1], wvv[j][1], acc[i][j]);
                    acc[i][j] = fmaf(xvv[i][2], wvv[j][2], acc[i][j]);
                    acc[i][j] = fmaf(xvv[i][3], wvv[j][3], acc[i][j]);
                }
        }

        if (pre) {
            const int bn_ = 1 - bcur;
            *(float4*)&smem[XOFF + bn_ * XSZ + xr * KC + xq] = xv;
            const float* q0 = (const float*)&wq0; const float* q1 = (const float*)&wq1;
            const float* q2 = (const float*)&wq2; const float* q3 = (const float*)&wq3;
#pragma unroll
            for (int i = 0; i < 4; ++i) {
                float2 lo; lo.x = q0[i]; lo.y = q1[i];
                float2 hi; hi.x = q2[i]; hi.y = q3[i];
                float* wd = &smem[bn_ * WSZ + (cb + i) * WP + kb];
                *(float2*)wd = lo;
                *(float2*)(wd + 2) = hi;
            }
        }
        __syncthreads();
    }

    // ---- logits -> LDS (reuse W buffer 0 region: 32*132 = 4224 < 4352) ----
#pragma unroll
    for (int i = 0; i < 4; ++i)
#pragma unroll
        for (int j = 0; j < 4; ++j)
            smem[(tb + i) * 132 + cg + 32 * j] = acc[i][j];
    __syncthreads();

    // ---- epilogue: wave per 8 tokens, lane = expert ----
    const int wvid = tid >> 6;
    const int lane = tid & 63;
    const float brl = br[lane], bnl = bn[lane];
    for (int it = 0; it < 8; ++it) {
        const int tl = wvid * 8 + it;
        const int tg = t0 + tl;
        float v  = smem[tl * 132 + lane] + brl;
        float nz = smem[tl * 132 + 64 + lane] + bnl;
        float sp = log1pf(expf(-fabsf(nz))) + fmaxf(nz, 0.f);   // stable softplus
        v += noise[(size_t)tg * EDIM + lane] * sp;

        float mx = v;
#pragma unroll
        for (int o = 32; o >= 1; o >>= 1) mx = fmaxf(mx, __shfl_xor(mx, o, 64));
        float p = expf(v - mx);
        float sm = p;
#pragma unroll
        for (int o = 32; o >= 1; o >>= 1) sm += __shfl_xor(sm, o, 64);
        float prob = p / sm;
        out[(size_t)NTOK * 16 + (size_t)tg * EDIM + lane] = prob;   // output 2

        float pv = prob;
        float wvals[8]; int widx[8]; float tsum = 0.f;
#pragma unroll
        for (int j = 0; j < 8; ++j) {
            float bv = pv; int bi = lane;
#pragma unroll
            for (int o = 32; o >= 1; o >>= 1) {
                float ov = __shfl_xor(bv, o, 64);
                int   oi = __shfl_xor(bi, o, 64);
                if (ov > bv || (ov == bv && oi < bi)) { bv = ov; bi = oi; }
            }
            wvals[j] = bv; widx[j] = bi; tsum += bv;
            if (lane == bi) pv = -1.0f;
        }
        if (lane < 8) {
            float myw = wvals[0]; int myi = widx[0];
#pragma unroll
            for (int j = 1; j < 8; ++j) if (lane == j) { myw = wvals[j]; myi = widx[j]; }
            out[(size_t)tg * 8 + lane] = myw / tsum;                       // output 0
            out[(size_t)NTOK * 8 + (size_t)tg * 8 + lane] = (float)myi;    // output 1
        }
    }
}

extern "C" void kernel_launch(void* const* d_in, const int* in_sizes, int n_in,
                              void* d_out, int out_size, void* d_ws, size_t ws_size,
                              hipStream_t stream) {
    const float* x     = (const float*)d_in[0];
    const float* noise = (const float*)d_in[1];
    const float* Wr    = (const float*)d_in[2];
    const float* br    = (const float*)d_in[3];
    const float* Wn    = (const float*)d_in[4];
    const float* bn    = (const float*)d_in[5];
    float* out = (float*)d_out;
    hipLaunchKernelGGL(router_fused, dim3(NTOK / MT), dim3(256), 0, stream,
                       x, noise, Wr, br, Wn, bn, out);
}

// Round 5
// 582.740 us; speedup vs baseline: 3.0888x; 3.0888x over previous
//
#include <hip/hip_runtime.h>
#include <math.h>
#include <stdint.h>

#define NTOK 16384
#define KD   4096
#define EDIM 64
#define MT   64                 // tokens per block
#define KC   64                 // k per chunk
#define NC   (KD / KC)          // 64 chunks
#define WSTR 132                // W tile row stride [k][WSTR]
#define XSTR 68                 // x tile row stride [tok][XSTR]
#define WOFF 0
#define XOFF (KC * WSTR)        /* 8448 */
#define SMEMF (XOFF + MT * XSTR) /* 12800 floats = 51.2 KB */

__global__ __launch_bounds__(512, 2)
void router_fused(const float* __restrict__ x,
                  const float* __restrict__ noise,
                  const float* __restrict__ Wr,
                  const float* __restrict__ br,
                  const float* __restrict__ Wn,
                  const float* __restrict__ bn,
                  float* __restrict__ out) {
    __shared__ float smem[SMEMF];
    const int tid = threadIdx.x;
    const int t0 = blockIdx.x * MT;

    // compute roles: thread = 4 tokens x 4 consecutive cols
    const int eb = (tid & 31) * 4;        // col base 0..124
    const int tb = (tid >> 5) * 4;        // token base 0..60

    // staging roles (512 threads)
    const int xr = tid >> 3;              // 0..63 token row
    const int xq = (tid & 7) * 8;         // 8 floats per thread
    const int wk = tid >> 3;              // 0..63 k row
    const int wc = (tid & 7) * 16;        // 16 floats per thread
    const float* xsrc = x + (size_t)(t0 + xr) * KD + xq;
    const float* wsrc = (wc < 64) ? (Wr + (size_t)wk * EDIM + wc)
                                  : (Wn + (size_t)wk * EDIM + (wc - 64));

    float acc[4][4];
#pragma unroll
    for (int i = 0; i < 4; ++i)
#pragma unroll
        for (int j = 0; j < 4; ++j) acc[i][j] = 0.f;

    // ---- prologue: load chunk 0 into regs, store to LDS ----
    float4 px0 = *(const float4*)(xsrc);
    float4 px1 = *(const float4*)(xsrc + 4);
    float4 pw0 = *(const float4*)(wsrc);
    float4 pw1 = *(const float4*)(wsrc + 4);
    float4 pw2 = *(const float4*)(wsrc + 8);
    float4 pw3 = *(const float4*)(wsrc + 12);
    {
        float* xd = &smem[XOFF + xr * XSTR + xq];
        *(float4*)xd = px0; *(float4*)(xd + 4) = px1;
        float* wd = &smem[WOFF + wk * WSTR + wc];
        *(float4*)wd = pw0; *(float4*)(wd + 4) = pw1;
        *(float4*)(wd + 8) = pw2; *(float4*)(wd + 12) = pw3;
    }

    for (int c = 0; c < NC; ++c) {
        __syncthreads();   // LDS tile ready
        const bool pre = (c + 1) < NC;
        if (pre) {
            const size_t ko = (size_t)(c + 1) * KC;
            px0 = *(const float4*)(xsrc + ko);
            px1 = *(const float4*)(xsrc + ko + 4);
            const float* wp = wsrc + ko * EDIM;
            pw0 = *(const float4*)(wp);
            pw1 = *(const float4*)(wp + 4);
            pw2 = *(const float4*)(wp + 8);
            pw3 = *(const float4*)(wp + 12);
        }

#pragma unroll 4
        for (int kk = 0; kk < KC; kk += 4) {
            float xv[4][4];
#pragma unroll
            for (int i = 0; i < 4; ++i)
                *(float4*)xv[i] = *(const float4*)&smem[XOFF + (tb + i) * XSTR + kk]; // broadcast
            float wv[4][4];
#pragma unroll
            for (int kp = 0; kp < 4; ++kp)
                *(float4*)wv[kp] = *(const float4*)&smem[WOFF + (kk + kp) * WSTR + eb];
            // strictly ascending k per accumulator (same chain as R1/R4 - passed twice)
#pragma unroll
            for (int i = 0; i < 4; ++i)
#pragma unroll
                for (int j = 0; j < 4; ++j) {
                    acc[i][j] = fmaf(xv[i][0], wv[0][j], acc[i][j]);
                    acc[i][j] = fmaf(xv[i][1], wv[1][j], acc[i][j]);
                    acc[i][j] = fmaf(xv[i][2], wv[2][j], acc[i][j]);
                    acc[i][j] = fmaf(xv[i][3], wv[3][j], acc[i][j]);
                }
        }

        __syncthreads();   // compute done; safe to overwrite LDS
        if (pre) {
            float* xd = &smem[XOFF + xr * XSTR + xq];
            *(float4*)xd = px0; *(float4*)(xd + 4) = px1;
            float* wd = &smem[WOFF + wk * WSTR + wc];
            *(float4*)wd = pw0; *(float4*)(wd + 4) = pw1;
            *(float4*)(wd + 8) = pw2; *(float4*)(wd + 12) = pw3;
        }
    }

    // ---- logits -> LDS (reuse W area: 64 x 132) ----
#pragma unroll
    for (int i = 0; i < 4; ++i)
        *(float4*)&smem[(tb + i) * WSTR + eb] = *(float4*)acc[i];
    __syncthreads();

    // ---- epilogue: wave per token, lane = expert ----
    const int wvid = tid >> 6;            // 0..7
    const int lane = tid & 63;
    const float brl = br[lane], bnl = bn[lane];
    for (int it = 0; it < 8; ++it) {
        const int tl = wvid * 8 + it;
        const int tg = t0 + tl;
        float v  = smem[tl * WSTR + lane] + brl;
        float nz = smem[tl * WSTR + 64 + lane] + bnl;
        float sp = log1pf(expf(-fabsf(nz))) + fmaxf(nz, 0.f);   // stable softplus
        v += noise[(size_t)tg * EDIM + lane] * sp;

        float mx = v;
#pragma unroll
        for (int o = 32; o >= 1; o >>= 1) mx = fmaxf(mx, __shfl_xor(mx, o, 64));
        float p = expf(v - mx);
        float sm = p;
#pragma unroll
        for (int o = 32; o >= 1; o >>= 1) sm += __shfl_xor(sm, o, 64);
        float prob = p / sm;
        out[(size_t)NTOK * 16 + (size_t)tg * EDIM + lane] = prob;   // output 2

        float pv = prob;
        float wvals[8]; int widx[8]; float tsum = 0.f;
#pragma unroll
        for (int j = 0; j < 8; ++j) {
            float bv = pv; int bi = lane;
#pragma unroll
            for (int o = 32; o >= 1; o >>= 1) {
                float ov = __shfl_xor(bv, o, 64);
                int   oi = __shfl_xor(bi, o, 64);
                if (ov > bv || (ov == bv && oi < bi)) { bv = ov; bi = oi; }
            }
            wvals[j] = bv; widx[j] = bi; tsum += bv;
            if (lane == bi) pv = -1.0f;
        }
        if (lane < 8) {
            float myw = wvals[0]; int myi = widx[0];
#pragma unroll
            for (int j = 1; j < 8; ++j) if (lane == j) { myw = wvals[j]; myi = widx[j]; }
            out[(size_t)tg * 8 + lane] = myw / tsum;                       // output 0
            out[(size_t)NTOK * 8 + (size_t)tg * 8 + lane] = (float)myi;    // output 1
        }
    }
}

extern "C" void kernel_launch(void* const* d_in, const int* in_sizes, int n_in,
                              void* d_out, int out_size, void* d_ws, size_t ws_size,
                              hipStream_t stream) {
    const float* x     = (const float*)d_in[0];
    const float* noise = (const float*)d_in[1];
    const float* Wr    = (const float*)d_in[2];
    const float* br    = (const float*)d_in[3];
    const float* Wn    = (const float*)d_in[4];
    const float* bn    = (const float*)d_in[5];
    float* out = (float*)d_out;
    hipLaunchKernelGGL(router_fused, dim3(NTOK / MT), dim3(512), 0, stream,
                       x, noise, Wr, br, Wn, bn, out);
}